// Round 1
// baseline (385.868 us; speedup 1.0000x reference)
//
#include <hip/hip_runtime.h>
#include <hip/hip_bf16.h>
#include <stdint.h>

#define IMG_H 96
#define IMG_W 96
#define IMG_C 3
#define PSZ   7
#define HO    90                 // 96-7+1
#define NPAT  8100               // 90*90
#define NPAD  8192
#define DDIM  147                // 3*7*7
#define KPAD  160                // padded K (mult of 32)
#define BATCH 4
#define TILE  128
#define ALPHA 0.05f

typedef __attribute__((ext_vector_type(8))) short short8;
typedef __attribute__((ext_vector_type(4))) float f32x4;

__device__ __forceinline__ void async16(const void* g, void* l) {
    __builtin_amdgcn_global_load_lds(
        (const __attribute__((address_space(1))) unsigned int*)g,
        (__attribute__((address_space(3))) unsigned int*)l,
        16, 0, 0);
}

// -------------------- patch extraction + squared norms --------------------
// one wave per patch; writes bf16 patch row [KPAD] (zero-padded) + fp32 norm
__global__ __launch_bounds__(256) void extract_patches(
    const float* __restrict__ img,          // [B][3][96][96]
    __hip_bfloat16* __restrict__ pat,       // [B][NPAD][KPAD]
    float* __restrict__ nrm)                // [B][NPAD]
{
    int wid  = threadIdx.x >> 6;
    int lane = threadIdx.x & 63;
    int pidx = blockIdx.x * 4 + wid;        // 0..8191
    int b    = blockIdx.y;
    if (pidx >= NPAD) return;
    const float* im = img + (size_t)b * (IMG_C * IMG_H * IMG_W);
    __hip_bfloat16* pp = pat + ((size_t)b * NPAD + pidx) * KPAD;
    int r = pidx / HO, c = pidx - r * HO;
    bool valid = pidx < NPAT;
    float ss = 0.f;
    for (int d = lane; d < KPAD; d += 64) {
        float v = 0.f;
        if (valid && d < DDIM) {
            int ch  = d / 49;
            int rem = d - ch * 49;
            int pr  = rem / 7, pc = rem - pr * 7;
            v = im[ch * (IMG_H * IMG_W) + (r + pr) * IMG_W + (c + pc)];
        }
        pp[d] = __float2bfloat16(v);
        ss += v * v;
    }
    for (int s = 32; s; s >>= 1) ss += __shfl_down(ss, s);
    if (lane == 0) nrm[(size_t)b * NPAD + pidx] = ss;
}

// -------------------- init min arrays to +inf bits --------------------
__global__ void init_mins(unsigned* __restrict__ row_min,
                          unsigned* __restrict__ col_min) {
    int i = blockIdx.x * blockDim.x + threadIdx.x;
    if (i < BATCH * NPAD) {
        row_min[i] = 0x7f800000u;
        col_min[i] = 0x7f800000u;
    }
}

// -------------------- fused GEMM + min epilogues --------------------
// PASS 1: row_min[j] = min_i max((y2[j]+x2[i]-2*cross)/D, 0)
// PASS 2: col_min[i] = min_j dist[j,i] / (row_min[j]+ALPHA)
template <int PASS>
__global__ __launch_bounds__(256, 2) void gemm_pass(
    const __hip_bfloat16* __restrict__ Xp,   // [B][NPAD][KPAD] columns i
    const __hip_bfloat16* __restrict__ Yp,   // [B][NPAD][KPAD] rows j
    const float* __restrict__ x2,
    const float* __restrict__ y2,
    unsigned* __restrict__ row_min,
    unsigned* __restrict__ col_min)
{
    __shared__ __align__(16) __hip_bfloat16 Alds[TILE * 32];  // rows (Yp)
    __shared__ __align__(16) __hip_bfloat16 Blds[TILE * 32];  // cols (Xp)
    __shared__ float y2s[TILE], x2s[TILE], rms[TILE];

    int bz  = blockIdx.z;
    int tI  = blockIdx.x;   // col tile
    int tJ  = blockIdx.y;   // row tile
    int tid = threadIdx.x;
    int wid = tid >> 6, lane = tid & 63;
    int wr = wid >> 1, wc = wid & 1;

    const __hip_bfloat16* Abase = Yp + ((size_t)bz * NPAD + tJ * TILE) * KPAD;
    const __hip_bfloat16* Bbase = Xp + ((size_t)bz * NPAD + tI * TILE) * KPAD;

    if (tid < TILE) {
        y2s[tid] = y2[(size_t)bz * NPAD + tJ * TILE + tid];
        if (PASS == 2) {
            float rm = __uint_as_float(row_min[(size_t)bz * NPAD + tJ * TILE + tid]);
            rms[tid] = 1.0f / (rm + ALPHA);  // +inf row -> 0, masked later
        }
    } else {
        int t = tid - TILE;
        x2s[t] = x2[(size_t)bz * NPAD + tI * TILE + t];
    }

    f32x4 acc[4][4] = {};
    int srow = (lane >> 2);          // + q*16
    int skel = (lane & 3) * 8;

    for (int k0 = 0; k0 < KPAD; k0 += 32) {
        // stage A/B 128x32 bf16 tiles: wave wid stages chunks {2wid, 2wid+1}
        for (int qq = 0; qq < 2; ++qq) {
            int q = wid * 2 + qq;
            int row = q * 16 + srow;
            async16(Abase + (size_t)row * KPAD + k0 + skel, &Alds[q * 512]);
            async16(Bbase + (size_t)row * KPAD + k0 + skel, &Blds[q * 512]);
        }
        __syncthreads();

        short8 a[4], bq[4];
        int arow = wr * 64 + (lane & 15);
        int brow = wc * 64 + (lane & 15);
        int koff = (lane >> 4) * 8;
        for (int m = 0; m < 4; ++m)
            a[m] = *(const short8*)&Alds[(arow + m * 16) * 32 + koff];
        for (int n = 0; n < 4; ++n)
            bq[n] = *(const short8*)&Blds[(brow + n * 16) * 32 + koff];
        for (int m = 0; m < 4; ++m)
            for (int n = 0; n < 4; ++n)
                acc[m][n] = __builtin_amdgcn_mfma_f32_16x16x32_bf16(
                    a[m], bq[n], acc[m][n], 0, 0, 0);
        __syncthreads();
    }

    const float invD = 1.0f / (float)DDIM;
    int rbase_l = wr * 64 + (lane >> 4) * 4;  // + m*16 + reg
    int cbase_l = wc * 64 + (lane & 15);      // + n*16
    int growb = tJ * TILE;
    int gcolb = tI * TILE;

    if (PASS == 1) {
        for (int m = 0; m < 4; ++m)
            for (int reg = 0; reg < 4; ++reg) {
                int lr = rbase_l + m * 16 + reg;
                float yv = y2s[lr];
                float rmin = __builtin_inff();
                for (int n = 0; n < 4; ++n) {
                    int lc = cbase_l + n * 16;
                    float dd = (yv + x2s[lc] - 2.0f * acc[m][n][reg]) * invD;
                    dd = fmaxf(dd, 0.0f);
                    if (gcolb + lc >= NPAT) dd = __builtin_inff();
                    rmin = fminf(rmin, dd);
                }
                for (int s = 1; s < 16; s <<= 1)
                    rmin = fminf(rmin, __shfl_xor(rmin, s));
                int grow = growb + lr;
                if ((lane & 15) == 0 && grow < NPAT)
                    atomicMin(&row_min[(size_t)bz * NPAD + grow],
                              __float_as_uint(rmin));
            }
    } else {
        for (int n = 0; n < 4; ++n) {
            int lc = cbase_l + n * 16;
            float xv = x2s[lc];
            float cmin = __builtin_inff();
            for (int m = 0; m < 4; ++m) {
                for (int reg = 0; reg < 4; ++reg) {
                    int lr = rbase_l + m * 16 + reg;
                    float dd = (y2s[lr] + xv - 2.0f * acc[m][n][reg]) * invD;
                    dd = fmaxf(dd, 0.0f);
                    float v = dd * rms[lr];
                    if (growb + lr >= NPAT) v = __builtin_inff();
                    cmin = fminf(cmin, v);
                }
            }
            cmin = fminf(cmin, __shfl_xor(cmin, 16));
            cmin = fminf(cmin, __shfl_xor(cmin, 32));
            int gcol = gcolb + lc;
            if ((lane >> 4) == 0 && gcol < NPAT)
                atomicMin(&col_min[(size_t)bz * NPAD + gcol],
                          __float_as_uint(cmin));
        }
    }
}

// -------------------- final mean --------------------
__global__ __launch_bounds__(256) void final_reduce(
    const unsigned* __restrict__ col_min, float* __restrict__ out)
{
    __shared__ float sdata[256];
    float s = 0.f;
    for (int idx = threadIdx.x; idx < BATCH * NPAT; idx += 256) {
        int b = idx / NPAT;
        int i = idx - b * NPAT;
        s += __uint_as_float(col_min[(size_t)b * NPAD + i]);
    }
    sdata[threadIdx.x] = s;
    __syncthreads();
    for (int t = 128; t; t >>= 1) {
        if (threadIdx.x < t) sdata[threadIdx.x] += sdata[threadIdx.x + t];
        __syncthreads();
    }
    if (threadIdx.x == 0) out[0] = sdata[0] / (float)(BATCH * NPAT);
}

extern "C" void kernel_launch(void* const* d_in, const int* in_sizes, int n_in,
                              void* d_out, int out_size, void* d_ws, size_t ws_size,
                              hipStream_t stream) {
    const float* x = (const float*)d_in[0];
    const float* y = (const float*)d_in[1];
    float* out = (float*)d_out;

    char* ws = (char*)d_ws;
    size_t patSz = (size_t)BATCH * NPAD * KPAD * sizeof(__hip_bfloat16); // 10.5 MB
    __hip_bfloat16* Xp = (__hip_bfloat16*)ws;
    __hip_bfloat16* Yp = (__hip_bfloat16*)(ws + patSz);
    float* x2 = (float*)(ws + 2 * patSz);
    float* y2 = x2 + BATCH * NPAD;
    unsigned* row_min = (unsigned*)(y2 + BATCH * NPAD);
    unsigned* col_min = row_min + BATCH * NPAD;

    dim3 eg(NPAD / 4, BATCH);
    extract_patches<<<eg, 256, 0, stream>>>(x, Xp, x2);
    extract_patches<<<eg, 256, 0, stream>>>(y, Yp, y2);

    init_mins<<<(BATCH * NPAD + 255) / 256, 256, 0, stream>>>(row_min, col_min);

    dim3 gg(NPAD / TILE, NPAD / TILE, BATCH);
    gemm_pass<1><<<gg, 256, 0, stream>>>(Xp, Yp, x2, y2, row_min, col_min);
    gemm_pass<2><<<gg, 256, 0, stream>>>(Xp, Yp, x2, y2, row_min, col_min);

    final_reduce<<<1, 256, 0, stream>>>(col_min, out);
}